// Round 10
// baseline (849.885 us; speedup 1.0000x reference)
//
#include <hip/hip_runtime.h>
#include <hip/hip_bf16.h>

#define B_ 4
#define G_ 4096
#define F_ 256
#define U_ 128

typedef __bf16 v8bf __attribute__((ext_vector_type(8)));
typedef float f32x4 __attribute__((ext_vector_type(4)));

__device__ __forceinline__ unsigned short f2bf(float x) {
    union { float f; unsigned u; } v; v.f = x;
    unsigned r = v.u + 0x7FFFu + ((v.u >> 16) & 1u);
    return (unsigned short)(r >> 16);
}

typedef const __attribute__((address_space(1))) unsigned int* gas_t;
typedef __attribute__((address_space(3))) unsigned int* las_t;

// async global->LDS, 16B/lane; LDS dest = uniform base + lane*16; global src per-lane
__device__ __forceinline__ void gld16(const void* g, const void* l) {
    __builtin_amdgcn_global_load_lds((gas_t)(unsigned long long)g,
                                     (las_t)(unsigned)(unsigned long long)l, 16, 0, 0);
}

#define WAITV(n) asm volatile("s_waitcnt vmcnt(" #n ")" ::: "memory")
#define LGKM0    asm volatile("s_waitcnt lgkmcnt(0)" ::: "memory")
#define SBAR     __builtin_amdgcn_s_barrier()
#define SCHED0   __builtin_amdgcn_sched_barrier(0)

// Fragment-major convention: [row16-blk][k32-blk][lane][8 bf16];
// lane = ((k>>3)&3)*16 + (row&15). One frag load = 1KB coalesced / contiguous LDS.

// LDS arena (73728 B -> 2 blocks/CU at 512 threads)
#define OFF_FG   0        // 2 x 8KB dbuf: Ff[g32] frags (attn B-side, term 1)
#define OFF_AJ   16384    // 2 x 8KB dbuf: Aj[g32] frags (attn B-side, term 2)
#define OFF_FT   32768    // 2 x 8KB dbuf: FfT[u128][g32] frags (agg B-side)
#define OFF_BA   49152    // 2 x 8KB dbuf: fused bias bf16 [g32][h128], 16B-XOR-swizzled rows
#define OFF_GT   65536    // 8KB: gate^T bf16 [h128][g32], swz ^((h>>2)&3)<<4
#define LDS_SZ   73728

// ---------------- prep: transpose w,w2 [256][128]f32 -> wT [128][256]bf16 ----------------
__global__ __launch_bounds__(256) void k_transpose_w(
    const float* __restrict__ w, const float* __restrict__ w2,
    unsigned short* __restrict__ wT, unsigned short* __restrict__ w2T)
{
    int bx = blockIdx.x;
    const float* src = (bx & 1) ? w2 : w;
    unsigned short* dst = (bx & 1) ? w2T : wT;
    int u = threadIdx.x & 127;
    int kseg = (threadIdx.x >> 7) + (bx >> 1) * 2;   // 0..15
    #pragma unroll
    for (int k = 0; k < 16; ++k) {
        int kk = kseg * 16 + k;
        dst[(size_t)u * F_ + kk] = f2bf(src[(size_t)kk * U_ + u]);
    }
}

// ---------------- prep: ai,aj [128][4096]f32 -> Ai/Aj fragment-major bf16 (1 MiB each) ---
__global__ __launch_bounds__(256) void k_transpose_aiaj(
    const float* __restrict__ ai, const float* __restrict__ aj,
    unsigned short* __restrict__ Ai, unsigned short* __restrict__ Aj)
{
    __shared__ unsigned short s_t[64 * 128];
    int blk = blockIdx.x;
    const float* src = (blk < 64) ? ai : aj;
    unsigned short* dst = (blk < 64) ? Ai : Aj;
    int gtile = (blk & 63) * 64;
    int tid = threadIdx.x;
    int gl = tid & 63, ub = tid >> 6;
    #pragma unroll
    for (int i = 0; i < 32; ++i) {
        int u = ub * 32 + i;
        float v = src[(size_t)u * G_ + gtile + gl];
        int ad = ((gl << 8) + (u << 1)) ^ ((gl & 7) << 4);
        *(unsigned short*)((char*)s_t + ad) = f2bf(v);
    }
    __syncthreads();
    int c = tid >> 4, sub = tid & 15;
    int g4l = c >> 2, k5 = c & 3;
    #pragma unroll
    for (int q = 0; q < 4; ++q) {
        int l = sub * 4 + q;
        int g = g4l * 16 + (l & 15);
        int u = k5 * 32 + (l >> 4) * 8;
        uint4 v = *(const uint4*)((const char*)s_t + (g << 8) + ((u << 1) ^ ((g & 7) << 4)));
        *(uint4*)(dst + (((size_t)((gtile >> 4) + g4l) * 4 + k5) * 64 + l) * 8) = v;
    }
}

// ---------------- prep: fused bias bf16: ct16[g][h] = bf16(b_a + 1e9*adj - 1e9) ----------
__global__ __launch_bounds__(256) void k_bias16(
    const float* __restrict__ adj, const float* __restrict__ ba,
    unsigned short* __restrict__ ct)
{
    size_t i = ((size_t)blockIdx.x * 256 + threadIdx.x) * 8;
    float4 a0 = *(const float4*)(adj + i);
    float4 a1 = *(const float4*)(adj + i + 4);
    float4 b0 = *(const float4*)(ba + i);
    float4 b1 = *(const float4*)(ba + i + 4);
    union { unsigned short s[8]; uint4 v; } o;
    o.s[0] = f2bf(fmaf(a0.x, 1e9f, -1e9f) + b0.x);
    o.s[1] = f2bf(fmaf(a0.y, 1e9f, -1e9f) + b0.y);
    o.s[2] = f2bf(fmaf(a0.z, 1e9f, -1e9f) + b0.z);
    o.s[3] = f2bf(fmaf(a0.w, 1e9f, -1e9f) + b0.w);
    o.s[4] = f2bf(fmaf(a1.x, 1e9f, -1e9f) + b1.x);
    o.s[5] = f2bf(fmaf(a1.y, 1e9f, -1e9f) + b1.y);
    o.s[6] = f2bf(fmaf(a1.z, 1e9f, -1e9f) + b1.z);
    o.s[7] = f2bf(fmaf(a1.w, 1e9f, -1e9f) + b1.w);
    *(uint4*)(ct + i) = o.v;
}

// ---------------- f = bf16(x@w) -> Ff/FfT fragment-major, g2 = f32(x@w_2) -> d_out -------
__global__ __launch_bounds__(256, 2) void k_gemm_f(
    const float* __restrict__ x,
    const unsigned short* __restrict__ wT, const unsigned short* __restrict__ w2T,
    unsigned short* __restrict__ Ff, unsigned short* __restrict__ FfT,
    float* __restrict__ g2_out)
{
    __shared__ unsigned short s_xa[128 * 128];
    __shared__ unsigned short s_w[128 * 128];
    __shared__ unsigned short s_w2[128 * 128];
    const int tid = threadIdx.x;
    const int lane = tid & 63, w = tid >> 6;
    const int l15 = lane & 15, l4 = lane >> 4;
    const int wm = w >> 1, wn = w & 1;
    const int mrow0 = blockIdx.x * 128;

    f32x4 zz = {0.f, 0.f, 0.f, 0.f};
    f32x4 accf[4][4], accg[4][4];
    #pragma unroll
    for (int i = 0; i < 4; ++i)
        #pragma unroll
        for (int j = 0; j < 4; ++j) { accf[i][j] = zz; accg[i][j] = zz; }

    for (int kc = 0; kc < 2; ++kc) {
        if (kc) __syncthreads();
        {   // stage x tile (f32 -> bf16, swizzled)
            int m = tid >> 1, half = tid & 1;
            const float* src = x + (size_t)(mrow0 + m) * F_ + kc * 128 + half * 64;
            unsigned tmp32[32];
            #pragma unroll
            for (int i = 0; i < 16; ++i) {
                float4 v = *(const float4*)(src + i * 4);
                tmp32[i * 2 + 0] = (unsigned)f2bf(v.x) | ((unsigned)f2bf(v.y) << 16);
                tmp32[i * 2 + 1] = (unsigned)f2bf(v.z) | ((unsigned)f2bf(v.w) << 16);
            }
            #pragma unroll
            for (int gi2 = 0; gi2 < 8; ++gi2) {
                int ad = (m << 8) + ((half * 128 + gi2 * 16) ^ ((m & 7) << 4));
                *(uint4*)((char*)s_xa + ad) = *(const uint4*)(tmp32 + gi2 * 4);
            }
        }
        #pragma unroll
        for (int i = 0; i < 8; ++i) {
            int c = w * 8 + i;
            int row = c * 4 + l4;
            int Wp = (l15 << 4) ^ ((row & 7) << 4);
            gld16((const char*)wT  + (size_t)row * 512 + kc * 256 + Wp, (const char*)s_w  + c * 1024);
            gld16((const char*)w2T + (size_t)row * 512 + kc * 256 + Wp, (const char*)s_w2 + c * 1024);
        }
        __syncthreads();
        #pragma unroll
        for (int ks = 0; ks < 4; ++ks) {
            int kb = 64 * ks + 16 * l4;
            v8bf a[4], b1[4], b2[4];
            #pragma unroll
            for (int mf = 0; mf < 4; ++mf) {
                int m = l15 + 16 * mf + 64 * wm;
                int ad = (m << 8) + (kb ^ ((m & 7) << 4));
                a[mf] = *(const v8bf*)((const char*)s_xa + ad);
            }
            #pragma unroll
            for (int nf = 0; nf < 4; ++nf) {
                int u = l15 + 16 * nf + 64 * wn;
                int ad = (u << 8) + (kb ^ ((u & 7) << 4));
                b1[nf] = *(const v8bf*)((const char*)s_w + ad);
                b2[nf] = *(const v8bf*)((const char*)s_w2 + ad);
            }
            #pragma unroll
            for (int mf = 0; mf < 4; ++mf)
                #pragma unroll
                for (int nf = 0; nf < 4; ++nf) {
                    accf[mf][nf] = __builtin_amdgcn_mfma_f32_16x16x32_bf16(a[mf], b1[nf], accf[mf][nf], 0, 0, 0);
                    accg[mf][nf] = __builtin_amdgcn_mfma_f32_16x16x32_bf16(a[mf], b2[nf], accg[mf][nf], 0, 0, 0);
                }
        }
    }
    const int b = mrow0 >> 12, gb = mrow0 & 4095;
    #pragma unroll
    for (int mf = 0; mf < 4; ++mf)
        #pragma unroll
        for (int nf = 0; nf < 4; ++nf)
            #pragma unroll
            for (int r = 0; r < 4; ++r) {
                int m = 4 * l4 + r + 16 * mf + 64 * wm;
                int u = l15 + 16 * nf + 64 * wn;
                g2_out[(size_t)(mrow0 + m) * U_ + u] = accg[mf][nf][r];
            }
    __syncthreads();
    #pragma unroll
    for (int mf = 0; mf < 4; ++mf)
        #pragma unroll
        for (int nf = 0; nf < 4; ++nf)
            #pragma unroll
            for (int r = 0; r < 4; ++r) {
                int m = 4 * l4 + r + 16 * mf + 64 * wm;
                int u = l15 + 16 * nf + 64 * wn;
                int ad = (m << 8) + ((u << 1) ^ ((m & 7) << 4));
                *(unsigned short*)((char*)s_xa + ad) = f2bf(accf[mf][nf][r]);
            }
    __syncthreads();
    {
        unsigned short* Ffb = Ff + (size_t)b * (G_ * U_);
        int c = tid >> 3, sub = tid & 7;
        int g4l = c >> 2, k5 = c & 3;
        #pragma unroll
        for (int q = 0; q < 8; ++q) {
            int l = sub * 8 + q;
            int m = g4l * 16 + (l & 15);
            int k = k5 * 32 + (l >> 4) * 8;
            uint4 v = *(const uint4*)((const char*)s_xa + (m << 8) + ((k << 1) ^ ((m & 7) << 4)));
            *(uint4*)(Ffb + (((size_t)((gb >> 4) + g4l) * 4 + k5) * 64 + l) * 8) = v;
        }
    }
    {
        unsigned short* FfTb = FfT + (size_t)b * (G_ * U_);
        int c = tid >> 3, sub = tid & 7;
        int u4 = c >> 2, g5l = c & 3;
        #pragma unroll
        for (int q = 0; q < 8; ++q) {
            int l = sub * 8 + q;
            int u = u4 * 16 + (l & 15);
            int g0l = g5l * 32 + (l >> 4) * 8;
            union { unsigned short s[8]; uint4 v; } pk;
            #pragma unroll
            for (int j = 0; j < 8; ++j) {
                int m = g0l + j;
                pk.s[j] = *(const unsigned short*)((const char*)s_xa + (m << 8) + ((u << 1) ^ ((m & 7) << 4)));
            }
            *(uint4*)(FfTb + (((size_t)u4 * 128 + (gb >> 5) + g5l) * 64 + l) * 8) = pk.v;
        }
    }
}

// ---------------- k_main (templated for phase ablation) ----------------
// V bitmask: 1 = attn MFMA, 2 = epilogue (bias+sigmoid+gate store+GT write), 4 = agg.
// REP = outer repeats of the 32-iter loop (ablation visibility; real launch uses REP=1).
// Staging + barrier skeleton identical in all variants; vmcnt counts adjusted per variant
// (stores only exist when V&2). Values for REP>1 / partial V are garbage; the final
// k_main_t<7,1> launch rewrites all of gate/part with correct values.
__device__ __forceinline__ void stage_all(const unsigned short* Ff_b, const unsigned short* Aj,
                                          const unsigned short* FfT_b, const unsigned short* ct,
                                          char* smem, int w, int lane, int gt, int htile, int slot)
{
    size_t off = ((((size_t)(gt >> 4) + (w >> 2)) * 4 + (w & 3)) * 64 + lane) * 16;
    gld16((const char*)Ff_b + off, smem + OFF_FG + slot * 8192 + w * 1024);
    gld16((const char*)Aj  + off, smem + OFF_AJ + slot * 8192 + w * 1024);
    gld16((const char*)FfT_b + (((size_t)w * 128 + (gt >> 5)) * 64 + lane) * 16,
          smem + OFF_FT + slot * 8192 + w * 1024);
    int row = 4 * w + (lane >> 4);
    int src = ((lane & 15) * 16) ^ ((row & 7) << 4);
    gld16((const char*)ct + ((size_t)(gt + row) * G_ + htile) * 2 + src,
          smem + OFF_BA + slot * 8192 + w * 1024);
}

template<int V, int REP>
__global__ __launch_bounds__(512, 4) void k_main_t(
    const unsigned short* __restrict__ Ff,
    const unsigned short* __restrict__ FfT,
    const unsigned short* __restrict__ Ai,
    const unsigned short* __restrict__ Aj,
    const unsigned short* __restrict__ ct16,
    float* __restrict__ gate_out,
    float* __restrict__ part)
{
    __shared__ __align__(1024) char smem[LDS_SZ];
    const int tid = threadIdx.x;
    const int lane = tid & 63, w = tid >> 6;
    const int l15 = lane & 15, l4 = lane >> 4;
    const int bid = blockIdx.x;
    const int xcd = bid & 7;
    const int rest = bid >> 3;
    const int b = rest & 3;
    const int tile = (rest >> 2) * 8 + xcd;
    const int split = tile & 3;
    const int htile = (tile >> 2) * 128;

    const unsigned short* Ff_b  = Ff  + (size_t)b * (G_ * U_);
    const unsigned short* FfT_b = FfT + (size_t)b * (G_ * U_);
    float* gate_b = gate_out + ((size_t)b << 24);

    #pragma unroll
    for (int i = 0; i < 4; ++i) {
        int c = 4 * w + i;
        size_t off = ((((size_t)(htile >> 4) + (c >> 2)) * 4 + (c & 3)) * 64 + lane) * 16;
        gld16((const char*)Ai + off, smem + c * 1024);
    }
    WAITV(0); SBAR;
    v8bf aih[4], fh[4];
    #pragma unroll
    for (int ks = 0; ks < 4; ++ks)
        aih[ks] = *(const v8bf*)(smem + (4 * w + ks) * 1024 + lane * 16);
    LGKM0; SBAR;
    #pragma unroll
    for (int i = 0; i < 4; ++i) {
        int c = 4 * w + i;
        size_t off = ((((size_t)(htile >> 4) + (c >> 2)) * 4 + (c & 3)) * 64 + lane) * 16;
        gld16((const char*)Ff_b + off, smem + c * 1024);
    }
    WAITV(0); SBAR;
    #pragma unroll
    for (int ks = 0; ks < 4; ++ks)
        fh[ks] = *(const v8bf*)(smem + (4 * w + ks) * 1024 + lane * 16);
    LGKM0; SBAR;
    stage_all(Ff_b, Aj, FfT_b, ct16, smem, w, lane, split * 1024, htile, 0);
    WAITV(0); SBAR;

    f32x4 zz = {0.f, 0.f, 0.f, 0.f};
    f32x4 agga[8];
    #pragma unroll
    for (int i = 0; i < 8; ++i) agga[i] = zz;

    for (int rep = 0; rep < REP; ++rep)
    for (int it = 0; it < 32; ++it) {
        const int gtile = split * 1024 + it * 32;
        const int itn = (it < 31) ? it + 1 : 31;
        const int gnext = split * 1024 + itn * 32;
        const int sl = it & 1, sln = (it + 1) & 1;

        stage_all(Ff_b, Aj, FfT_b, ct16, smem, w, lane, gnext, htile, sln);

        // B1: stage(it) ready. Outstanding after wait: stage(it+1)=4 (+2 stores if V&2)
        if constexpr ((V & 2) != 0) { WAITV(6); } else { WAITV(4); }
        LGKM0; SBAR; SCHED0;

        f32x4 acc[2] = {zz, zz};
        if constexpr ((V & 1) != 0) {
            const char* bfg = smem + OFF_FG + sl * 8192;
            const char* baj = smem + OFF_AJ + sl * 8192;
            #pragma unroll
            for (int ks = 0; ks < 4; ++ks) {
                #pragma unroll
                for (int nf = 0; nf < 2; ++nf) {
                    v8bf fgv = *(const v8bf*)(bfg + (nf * 4 + ks) * 1024 + lane * 16);
                    v8bf ajv = *(const v8bf*)(baj + (nf * 4 + ks) * 1024 + lane * 16);
                    acc[nf] = __builtin_amdgcn_mfma_f32_16x16x32_bf16(aih[ks], fgv, acc[nf], 0, 0, 0);
                    acc[nf] = __builtin_amdgcn_mfma_f32_16x16x32_bf16(fh[ks],  ajv, acc[nf], 0, 0, 0);
                }
            }
        }
        if constexpr ((V & 1) != 0 && (V & 2) == 0) {
            // keep attn MFMAs live without epilogue (DCE guard, rule #17)
            #pragma unroll
            for (int nf = 0; nf < 2; ++nf)
                asm volatile("" :: "v"(acc[nf][0]), "v"(acc[nf][1]), "v"(acc[nf][2]), "v"(acc[nf][3]));
        }

        if constexpr ((V & 2) != 0) {
            #pragma unroll
            for (int nf = 0; nf < 2; ++nf) {
                int g = 16 * nf + l15;
                int h0 = 16 * w + 4 * l4;
                ushort4 bu = *(const ushort4*)(smem + OFF_BA + sl * 8192 + g * 256 +
                                               ((h0 * 2) ^ ((g & 7) << 4)));
                f32x4 gs;
                #pragma unroll
                for (int r = 0; r < 4; ++r) {
                    union { unsigned u; float f; } cv;
                    cv.u = ((unsigned)(&bu.x)[r]) << 16;
                    float attnv = acc[nf][r] + cv.f;
                    float e = __expf(-attnv);
                    float gv = __builtin_amdgcn_rcpf(1.0f + e);
                    gs[r] = gv;
                    int hL = h0 + r;
                    *(unsigned short*)(smem + OFF_GT + hL * 64 +
                                       ((g * 2) ^ (((hL >> 2) & 3) << 4))) = f2bf(gv);
                }
                *(f32x4*)(gate_b + (size_t)(gtile + g) * G_ + htile + h0) = gs;
            }
        }

        LGKM0; SBAR; SCHED0;

        if constexpr ((V & 4) != 0) {
            int hr = 16 * w + l15;
            v8bf ag = *(const v8bf*)(smem + OFF_GT + hr * 64 +
                                     ((l4 * 16) ^ (((hr >> 2) & 3) << 4)));
            #pragma unroll
            for (int u4 = 0; u4 < 8; ++u4) {
                v8bf ft = *(const v8bf*)(smem + OFF_FT + sl * 8192 + u4 * 1024 + lane * 16);
                agga[u4] = __builtin_amdgcn_mfma_f32_16x16x32_bf16(ag, ft, agga[u4], 0, 0, 0);
            }
        }
    }

    if constexpr ((V & 4) != 0) {
        #pragma unroll
        for (int u4 = 0; u4 < 8; ++u4)
            #pragma unroll
            for (int r = 0; r < 4; ++r) {
                int h = htile + 16 * w + 4 * l4 + r;
                int u = 16 * u4 + l15;
                part[(((size_t)b * 4 + split) << 19) + (size_t)h * U_ + u] = agga[u4][r];
            }
    }
}

// ---------------- reduce: out = relu(part0..3 + g2) (g2 already in d_out) ----------------
__global__ __launch_bounds__(256) void k_reduce(const float4* __restrict__ part, float4* __restrict__ outio)
{
    int i = blockIdx.x * 256 + threadIdx.x;     // 0..524287 float4s
    int fb = i >> 17, r = i & 0x1FFFF;
    const float4* p = part + (((size_t)fb * 4) << 17) + r;
    float4 p0 = p[0];
    float4 p1 = p[(size_t)1 << 17];
    float4 p2 = p[(size_t)2 << 17];
    float4 p3 = p[(size_t)3 << 17];
    float4 g = outio[i];
    float4 o;
    o.x = fmaxf(p0.x + p1.x + p2.x + p3.x + g.x, 0.f);
    o.y = fmaxf(p0.y + p1.y + p2.y + p3.y + g.y, 0.f);
    o.z = fmaxf(p0.z + p1.z + p2.z + p3.z + g.z, 0.f);
    o.w = fmaxf(p0.w + p1.w + p2.w + p3.w + g.w, 0.f);
    outio[i] = o;
}

extern "C" void kernel_launch(void* const* d_in, const int* in_sizes, int n_in,
                              void* d_out, int out_size, void* d_ws, size_t ws_size,
                              hipStream_t stream)
{
    (void)in_sizes; (void)n_in; (void)out_size; (void)ws_size;
    const float* x   = (const float*)d_in[0];
    const float* adj = (const float*)d_in[1];
    const float* w   = (const float*)d_in[2];
    const float* ai  = (const float*)d_in[3];
    const float* aj  = (const float*)d_in[4];
    const float* w2  = (const float*)d_in[5];
    const float* ba  = (const float*)d_in[6];

    char* ws = (char*)d_ws;
    unsigned short* Ff  = (unsigned short*)(ws);                        // 4 MiB
    unsigned short* FfT = (unsigned short*)(ws + ((size_t)4 << 20));    // 4 MiB
    unsigned short* Ai  = (unsigned short*)(ws + ((size_t)8 << 20));    // 1 MiB
    unsigned short* Aj  = (unsigned short*)(ws + ((size_t)9 << 20));    // 1 MiB
    unsigned short* wT  = (unsigned short*)(ws + ((size_t)10 << 20));   // 64 KiB
    unsigned short* w2T = (unsigned short*)(ws + ((size_t)10 << 20) + (1 << 17));
    float* part         = (float*)(ws + ((size_t)12 << 20));            // 32 MiB [B][4][G][U]
    unsigned short* ct16= (unsigned short*)(ws + ((size_t)44 << 20));   // 32 MiB bf16 fused bias

    float* out  = (float*)d_out;                       // [B*G*U]
    float* gate = out + (size_t)B_ * G_ * U_;          // [B*G*G]

    k_transpose_w   <<<dim3(16),   dim3(256), 0, stream>>>(w, w2, wT, w2T);
    k_transpose_aiaj<<<dim3(128),  dim3(256), 0, stream>>>(ai, aj, Ai, Aj);
    k_bias16        <<<dim3(8192), dim3(256), 0, stream>>>(adj, ba, ct16);
    k_gemm_f        <<<dim3(128),  dim3(256), 0, stream>>>(x, wT, w2T, Ff, FfT, out);

    // ---- ABLATION dispatches (diagnostic; outputs overwritten by the real launch) ----
    k_main_t<0, 4><<<dim3(512), dim3(512), 0, stream>>>(Ff, FfT, Ai, Aj, ct16, gate, part); // skeleton x4
    k_main_t<1, 3><<<dim3(512), dim3(512), 0, stream>>>(Ff, FfT, Ai, Aj, ct16, gate, part); // +attn x3
    k_main_t<3, 2><<<dim3(512), dim3(512), 0, stream>>>(Ff, FfT, Ai, Aj, ct16, gate, part); // +epilogue x2
    k_main_t<7, 2><<<dim3(512), dim3(512), 0, stream>>>(Ff, FfT, Ai, Aj, ct16, gate, part); // full x2

    // ---- real computation ----
    k_main_t<7, 1><<<dim3(512), dim3(512), 0, stream>>>(Ff, FfT, Ai, Aj, ct16, gate, part);
    k_reduce        <<<dim3(2048), dim3(256), 0, stream>>>((const float4*)part, (float4*)out);
}

// Round 11
// 158.814 us; speedup vs baseline: 5.3514x; 5.3514x over previous
//
#include <hip/hip_runtime.h>
#include <hip/hip_bf16.h>

#define B_ 4
#define G_ 4096
#define F_ 256
#define U_ 128

typedef __bf16 v8bf __attribute__((ext_vector_type(8)));
typedef float f32x4 __attribute__((ext_vector_type(4)));

__device__ __forceinline__ unsigned short f2bf(float x) {
    union { float f; unsigned u; } v; v.f = x;
    unsigned r = v.u + 0x7FFFu + ((v.u >> 16) & 1u);
    return (unsigned short)(r >> 16);
}
__device__ __forceinline__ float bf2f(unsigned short s) {
    union { unsigned u; float f; } v; v.u = ((unsigned)s) << 16; return v.f;
}

typedef const __attribute__((address_space(1))) unsigned int* gas_t;
typedef __attribute__((address_space(3))) unsigned int* las_t;

// async global->LDS, 16B/lane; LDS dest = uniform base + lane*16; global src per-lane
__device__ __forceinline__ void gld16(const void* g, const void* l) {
    __builtin_amdgcn_global_load_lds((gas_t)(unsigned long long)g,
                                     (las_t)(unsigned)(unsigned long long)l, 16, 0, 0);
}

#define WAITV(n) asm volatile("s_waitcnt vmcnt(" #n ")" ::: "memory")
#define LGKM0    asm volatile("s_waitcnt lgkmcnt(0)" ::: "memory")
#define SBAR     __builtin_amdgcn_s_barrier()
#define SCHED0   __builtin_amdgcn_sched_barrier(0)

// Fragment-major convention: [row16-blk][k32-blk][lane][8 bf16];
// lane = ((k>>3)&3)*16 + (row&15). One frag load = 1KB coalesced / contiguous LDS.

// LDS arena (57344 B -> 2 blocks/CU at 256 threads; FT is direct-from-L2 this round)
#define OFF_FG   0        // 2 x 8KB dbuf: Ff[g32] frags (attn B-side, term 1)
#define OFF_AJ   16384    // 2 x 8KB dbuf: Aj[g32] frags (attn B-side, term 2)
#define OFF_BA   32768    // 2 x 8KB dbuf: fused bias bf16 [g32][h128], 16B-XOR-swizzled rows
#define OFF_GT   49152    // 8KB: gate^T bf16 [h128][g32], swz ^((h>>2)&3)<<4
#define LDS_SZ   57344

// ---------------- prep: transpose w,w2 [256][128]f32 -> wT [128][256]bf16 ----------------
__global__ __launch_bounds__(256) void k_transpose_w(
    const float* __restrict__ w, const float* __restrict__ w2,
    unsigned short* __restrict__ wT, unsigned short* __restrict__ w2T)
{
    int bx = blockIdx.x;
    const float* src = (bx & 1) ? w2 : w;
    unsigned short* dst = (bx & 1) ? w2T : wT;
    int u = threadIdx.x & 127;
    int kseg = (threadIdx.x >> 7) + (bx >> 1) * 2;   // 0..15
    #pragma unroll
    for (int k = 0; k < 16; ++k) {
        int kk = kseg * 16 + k;
        dst[(size_t)u * F_ + kk] = f2bf(src[(size_t)kk * U_ + u]);
    }
}

// ---------------- prep: ai,aj [128][4096]f32 -> Ai/Aj fragment-major bf16 (1 MiB each) ---
__global__ __launch_bounds__(256) void k_transpose_aiaj(
    const float* __restrict__ ai, const float* __restrict__ aj,
    unsigned short* __restrict__ Ai, unsigned short* __restrict__ Aj)
{
    __shared__ unsigned short s_t[64 * 128];
    int blk = blockIdx.x;
    const float* src = (blk < 64) ? ai : aj;
    unsigned short* dst = (blk < 64) ? Ai : Aj;
    int gtile = (blk & 63) * 64;
    int tid = threadIdx.x;
    int gl = tid & 63, ub = tid >> 6;
    #pragma unroll
    for (int i = 0; i < 32; ++i) {
        int u = ub * 32 + i;
        float v = src[(size_t)u * G_ + gtile + gl];
        int ad = ((gl << 8) + (u << 1)) ^ ((gl & 7) << 4);
        *(unsigned short*)((char*)s_t + ad) = f2bf(v);
    }
    __syncthreads();
    int c = tid >> 4, sub = tid & 15;
    int g4l = c >> 2, k5 = c & 3;
    #pragma unroll
    for (int q = 0; q < 4; ++q) {
        int l = sub * 4 + q;
        int g = g4l * 16 + (l & 15);
        int u = k5 * 32 + (l >> 4) * 8;
        uint4 v = *(const uint4*)((const char*)s_t + (g << 8) + ((u << 1) ^ ((g & 7) << 4)));
        *(uint4*)(dst + (((size_t)((gtile >> 4) + g4l) * 4 + k5) * 64 + l) * 8) = v;
    }
}

// ---------------- prep: fused bias bf16: ct16[g][h] = bf16(b_a + 1e9*adj - 1e9) ----------
__global__ __launch_bounds__(256) void k_bias16(
    const float* __restrict__ adj, const float* __restrict__ ba,
    unsigned short* __restrict__ ct)
{
    size_t i = ((size_t)blockIdx.x * 256 + threadIdx.x) * 8;
    float4 a0 = *(const float4*)(adj + i);
    float4 a1 = *(const float4*)(adj + i + 4);
    float4 b0 = *(const float4*)(ba + i);
    float4 b1 = *(const float4*)(ba + i + 4);
    union { unsigned short s[8]; uint4 v; } o;
    o.s[0] = f2bf(fmaf(a0.x, 1e9f, -1e9f) + b0.x);
    o.s[1] = f2bf(fmaf(a0.y, 1e9f, -1e9f) + b0.y);
    o.s[2] = f2bf(fmaf(a0.z, 1e9f, -1e9f) + b0.z);
    o.s[3] = f2bf(fmaf(a0.w, 1e9f, -1e9f) + b0.w);
    o.s[4] = f2bf(fmaf(a1.x, 1e9f, -1e9f) + b1.x);
    o.s[5] = f2bf(fmaf(a1.y, 1e9f, -1e9f) + b1.y);
    o.s[6] = f2bf(fmaf(a1.z, 1e9f, -1e9f) + b1.z);
    o.s[7] = f2bf(fmaf(a1.w, 1e9f, -1e9f) + b1.w);
    *(uint4*)(ct + i) = o.v;
}

// ---------------- f = bf16(x@w) -> Ff/FfT fragment-major, g2 = f32(x@w_2) -> d_out -------
__global__ __launch_bounds__(256, 2) void k_gemm_f(
    const float* __restrict__ x,
    const unsigned short* __restrict__ wT, const unsigned short* __restrict__ w2T,
    unsigned short* __restrict__ Ff, unsigned short* __restrict__ FfT,
    float* __restrict__ g2_out)
{
    __shared__ unsigned short s_xa[128 * 128];
    __shared__ unsigned short s_w[128 * 128];
    __shared__ unsigned short s_w2[128 * 128];
    const int tid = threadIdx.x;
    const int lane = tid & 63, w = tid >> 6;
    const int l15 = lane & 15, l4 = lane >> 4;
    const int wm = w >> 1, wn = w & 1;
    const int mrow0 = blockIdx.x * 128;

    f32x4 zz = {0.f, 0.f, 0.f, 0.f};
    f32x4 accf[4][4], accg[4][4];
    #pragma unroll
    for (int i = 0; i < 4; ++i)
        #pragma unroll
        for (int j = 0; j < 4; ++j) { accf[i][j] = zz; accg[i][j] = zz; }

    for (int kc = 0; kc < 2; ++kc) {
        if (kc) __syncthreads();
        {   // stage x tile (f32 -> bf16, swizzled)
            int m = tid >> 1, half = tid & 1;
            const float* src = x + (size_t)(mrow0 + m) * F_ + kc * 128 + half * 64;
            unsigned tmp32[32];
            #pragma unroll
            for (int i = 0; i < 16; ++i) {
                float4 v = *(const float4*)(src + i * 4);
                tmp32[i * 2 + 0] = (unsigned)f2bf(v.x) | ((unsigned)f2bf(v.y) << 16);
                tmp32[i * 2 + 1] = (unsigned)f2bf(v.z) | ((unsigned)f2bf(v.w) << 16);
            }
            #pragma unroll
            for (int gi2 = 0; gi2 < 8; ++gi2) {
                int ad = (m << 8) + ((half * 128 + gi2 * 16) ^ ((m & 7) << 4));
                *(uint4*)((char*)s_xa + ad) = *(const uint4*)(tmp32 + gi2 * 4);
            }
        }
        #pragma unroll
        for (int i = 0; i < 8; ++i) {
            int c = w * 8 + i;
            int row = c * 4 + l4;
            int Wp = (l15 << 4) ^ ((row & 7) << 4);
            gld16((const char*)wT  + (size_t)row * 512 + kc * 256 + Wp, (const char*)s_w  + c * 1024);
            gld16((const char*)w2T + (size_t)row * 512 + kc * 256 + Wp, (const char*)s_w2 + c * 1024);
        }
        __syncthreads();
        #pragma unroll
        for (int ks = 0; ks < 4; ++ks) {
            int kb = 64 * ks + 16 * l4;
            v8bf a[4], b1[4], b2[4];
            #pragma unroll
            for (int mf = 0; mf < 4; ++mf) {
                int m = l15 + 16 * mf + 64 * wm;
                int ad = (m << 8) + (kb ^ ((m & 7) << 4));
                a[mf] = *(const v8bf*)((const char*)s_xa + ad);
            }
            #pragma unroll
            for (int nf = 0; nf < 4; ++nf) {
                int u = l15 + 16 * nf + 64 * wn;
                int ad = (u << 8) + (kb ^ ((u & 7) << 4));
                b1[nf] = *(const v8bf*)((const char*)s_w + ad);
                b2[nf] = *(const v8bf*)((const char*)s_w2 + ad);
            }
            #pragma unroll
            for (int mf = 0; mf < 4; ++mf)
                #pragma unroll
                for (int nf = 0; nf < 4; ++nf) {
                    accf[mf][nf] = __builtin_amdgcn_mfma_f32_16x16x32_bf16(a[mf], b1[nf], accf[mf][nf], 0, 0, 0);
                    accg[mf][nf] = __builtin_amdgcn_mfma_f32_16x16x32_bf16(a[mf], b2[nf], accg[mf][nf], 0, 0, 0);
                }
        }
    }
    const int b = mrow0 >> 12, gb = mrow0 & 4095;
    #pragma unroll
    for (int mf = 0; mf < 4; ++mf)
        #pragma unroll
        for (int nf = 0; nf < 4; ++nf)
            #pragma unroll
            for (int r = 0; r < 4; ++r) {
                int m = 4 * l4 + r + 16 * mf + 64 * wm;
                int u = l15 + 16 * nf + 64 * wn;
                g2_out[(size_t)(mrow0 + m) * U_ + u] = accg[mf][nf][r];
            }
    __syncthreads();
    #pragma unroll
    for (int mf = 0; mf < 4; ++mf)
        #pragma unroll
        for (int nf = 0; nf < 4; ++nf)
            #pragma unroll
            for (int r = 0; r < 4; ++r) {
                int m = 4 * l4 + r + 16 * mf + 64 * wm;
                int u = l15 + 16 * nf + 64 * wn;
                int ad = (m << 8) + ((u << 1) ^ ((m & 7) << 4));
                *(unsigned short*)((char*)s_xa + ad) = f2bf(accf[mf][nf][r]);
            }
    __syncthreads();
    {
        unsigned short* Ffb = Ff + (size_t)b * (G_ * U_);
        int c = tid >> 3, sub = tid & 7;
        int g4l = c >> 2, k5 = c & 3;
        #pragma unroll
        for (int q = 0; q < 8; ++q) {
            int l = sub * 8 + q;
            int m = g4l * 16 + (l & 15);
            int k = k5 * 32 + (l >> 4) * 8;
            uint4 v = *(const uint4*)((const char*)s_xa + (m << 8) + ((k << 1) ^ ((m & 7) << 4)));
            *(uint4*)(Ffb + (((size_t)((gb >> 4) + g4l) * 4 + k5) * 64 + l) * 8) = v;
        }
    }
    {
        unsigned short* FfTb = FfT + (size_t)b * (G_ * U_);
        int c = tid >> 3, sub = tid & 7;
        int u4 = c >> 2, g5l = c & 3;
        #pragma unroll
        for (int q = 0; q < 8; ++q) {
            int l = sub * 8 + q;
            int u = u4 * 16 + (l & 15);
            int g0l = g5l * 32 + (l >> 4) * 8;
            union { unsigned short s[8]; uint4 v; } pk;
            #pragma unroll
            for (int j = 0; j < 8; ++j) {
                int m = g0l + j;
                pk.s[j] = *(const unsigned short*)((const char*)s_xa + (m << 8) + ((u << 1) ^ ((m & 7) << 4)));
            }
            *(uint4*)(FfTb + (((size_t)u4 * 128 + (gb >> 5) + g5l) * 64 + l) * 8) = pk.v;
        }
    }
}

// ---------------- k_main helpers ----------------
// Stage FG + AJ + BA for tile gt into buffer `slot`: 6 gld16/thread (4 waves, 256 thr).
__device__ __forceinline__ void stage_all(const unsigned short* Ff_b, const unsigned short* Aj,
                                          const unsigned short* ct, char* smem,
                                          int w, int lane, int gt, int htile, int slot)
{
    #pragma unroll
    for (int i = 0; i < 2; ++i) {
        int c = 2 * w + i;                  // 0..7
        size_t off = ((((size_t)(gt >> 4) + (c >> 2)) * 4 + (c & 3)) * 64 + lane) * 16;
        gld16((const char*)Ff_b + off, smem + OFF_FG + slot * 8192 + c * 1024);
        gld16((const char*)Aj  + off, smem + OFF_AJ + slot * 8192 + c * 1024);
        int row = 4 * c + (lane >> 4);
        int src = ((lane & 15) * 16) ^ ((row & 7) << 4);
        gld16((const char*)ct + ((size_t)(gt + row) * G_ + htile) * 2 + src,
              smem + OFF_BA + slot * 8192 + c * 1024);
    }
}

// 256 thr / 4 waves; wave w owns h-rows [32w,32w+32). Tile: 128h x 32g per iter, 32 iters.
// Per-thread VMEM order per iter:
//   [1] ft(it) 8 global->reg   [2] stage(it+1) 6 gld16   B1   attn   epi[4 nt-stores]   B2   agg
// FIFO at B1(it): [stage(it)6][stores(it-1)4][ft(it)8][stage(it+1)6] -> WAITV(18) retires
// exactly stage(it); stores and ft are never forced. ft reg use after B2 gets a
// compiler-counted vmcnt(~10) that also never forces stores.
__global__ __launch_bounds__(256, 2) void k_main(
    const unsigned short* __restrict__ Ff,   // [B] frag-major f [g4][k5][lane][8]
    const unsigned short* __restrict__ FfT,  // [B] frag-major fT [u4][g5][lane][8]
    const unsigned short* __restrict__ Ai,   // frag-major aiT
    const unsigned short* __restrict__ Aj,   // frag-major ajT
    const unsigned short* __restrict__ ct16, // [G][G] bf16 fused bias (b_a - 1e9*(1-adj))
    float* __restrict__ gate_out,            // [B][G][G] f32
    float* __restrict__ part)                // [B][4][G][U] f32
{
    __shared__ __align__(1024) char smem[LDS_SZ];
    const int tid = threadIdx.x;
    const int lane = tid & 63, w = tid >> 6;     // w in 0..3
    const int l15 = lane & 15, l4 = lane >> 4;
    // Same-b XCD clustering: per-XCD L2 working set = Ff_b + FfT_b + Ai + Aj = 4 MB.
    const int bid = blockIdx.x;
    const int xcd = bid & 7;
    const int b = xcd >> 1;                      // 2 XCDs per batch
    const int tile = (bid >> 3) * 2 + (xcd & 1); // 0..127
    const int split = tile & 3;
    const int htile = (tile >> 2) * 128;

    const unsigned short* Ff_b  = Ff  + (size_t)b * (G_ * U_);
    const unsigned short* FfT_b = FfT + (size_t)b * (G_ * U_);
    float* gate_b = gate_out + ((size_t)b << 24);

    // ---- prologue: Ai[htile] then Ff[htile] via LDS into per-wave registers (h32/wave) ----
    #pragma unroll
    for (int i = 0; i < 8; ++i) {
        int c = 8 * w + i;                  // 0..31
        size_t off = ((((size_t)(htile >> 4) + (c >> 2)) * 4 + (c & 3)) * 64 + lane) * 16;
        gld16((const char*)Ai + off, smem + c * 1024);
    }
    WAITV(0); SBAR;
    v8bf aih[2][4], fh[2][4];
    #pragma unroll
    for (int hf = 0; hf < 2; ++hf)
        #pragma unroll
        for (int ks = 0; ks < 4; ++ks)
            aih[hf][ks] = *(const v8bf*)(smem + (8 * w + 4 * hf + ks) * 1024 + lane * 16);
    LGKM0; SBAR;
    #pragma unroll
    for (int i = 0; i < 8; ++i) {
        int c = 8 * w + i;
        size_t off = ((((size_t)(htile >> 4) + (c >> 2)) * 4 + (c & 3)) * 64 + lane) * 16;
        gld16((const char*)Ff_b + off, smem + c * 1024);
    }
    WAITV(0); SBAR;
    #pragma unroll
    for (int hf = 0; hf < 2; ++hf)
        #pragma unroll
        for (int ks = 0; ks < 4; ++ks)
            fh[hf][ks] = *(const v8bf*)(smem + (8 * w + 4 * hf + ks) * 1024 + lane * 16);
    LGKM0; SBAR;
    // prime iter 0
    stage_all(Ff_b, Aj, ct16, smem, w, lane, split * 1024, htile, 0);
    WAITV(0); SBAR;

    f32x4 zz = {0.f, 0.f, 0.f, 0.f};
    f32x4 agga[2][8];
    #pragma unroll
    for (int i = 0; i < 2; ++i)
        #pragma unroll
        for (int j = 0; j < 8; ++j) agga[i][j] = zz;

    for (int it = 0; it < 32; ++it) {
        const int gtile = split * 1024 + it * 32;
        const int itn = (it < 31) ? it + 1 : 31;          // clamp: same op count, no OOB
        const int gnext = split * 1024 + itn * 32;
        const int sl = it & 1, sln = (it + 1) & 1;

        // [1] ft(it): agg B-frags direct from L2 (FfT_b resident on this XCD)
        v8bf ft[8];
        #pragma unroll
        for (int u4 = 0; u4 < 8; ++u4)
            ft[u4] = *(const v8bf*)(FfT_b + (((size_t)u4 * 128 + (gtile >> 5)) * 64 + lane) * 8);

        // [2] stage(it+1) -> buffer sln
        stage_all(Ff_b, Aj, ct16, smem, w, lane, gnext, htile, sln);

        // [B1] stage(it) in LDS; own prior-iter LDS reads drained (GT overwrite safe)
        WAITV(18); LGKM0; SBAR; SCHED0;

        // ---- attn: acc[h][g] = ai[:,h]·f[g] + f[h]·aj[:,g]  (32h x 32g per wave) ----
        f32x4 acc[2][2];
        #pragma unroll
        for (int i = 0; i < 2; ++i)
            #pragma unroll
            for (int j = 0; j < 2; ++j) acc[i][j] = zz;
        {
            const char* bfg = smem + OFF_FG + sl * 8192;
            const char* baj = smem + OFF_AJ + sl * 8192;
            #pragma unroll
            for (int ks = 0; ks < 4; ++ks) {
                v8bf fgv[2], ajv[2];
                #pragma unroll
                for (int gf = 0; gf < 2; ++gf) {
                    fgv[gf] = *(const v8bf*)(bfg + (gf * 4 + ks) * 1024 + lane * 16);
                    ajv[gf] = *(const v8bf*)(baj + (gf * 4 + ks) * 1024 + lane * 16);
                }
                #pragma unroll
                for (int hf = 0; hf < 2; ++hf)
                    #pragma unroll
                    for (int gf = 0; gf < 2; ++gf) {
                        acc[hf][gf] = __builtin_amdgcn_mfma_f32_16x16x32_bf16(aih[hf][ks], fgv[gf], acc[hf][gf], 0, 0, 0);
                        acc[hf][gf] = __builtin_amdgcn_mfma_f32_16x16x32_bf16(fh[hf][ks],  ajv[gf], acc[hf][gf], 0, 0, 0);
                    }
            }
        }

        // ---- epilogue: fused bias + sigmoid -> gate (nt f32x4) + gate^T (LDS bf16) ----
        #pragma unroll
        for (int gf = 0; gf < 2; ++gf)
            #pragma unroll
            for (int hf = 0; hf < 2; ++hf) {
                int g = 16 * gf + l15;               // tile-local g row
                int h0 = 32 * w + 16 * hf + 4 * l4;  // htile-local h
                ushort4 bu = *(const ushort4*)(smem + OFF_BA + sl * 8192 + g * 256 +
                                               ((h0 * 2) ^ ((g & 7) << 4)));
                f32x4 gs;
                #pragma unroll
                for (int r = 0; r < 4; ++r) {
                    float attnv = acc[hf][gf][r] + bf2f((&bu.x)[r]);
                    float e = __expf(-attnv);
                    float gv = __builtin_amdgcn_rcpf(1.0f + e);   // non-edge -> exactly 0
                    gs[r] = gv;
                    int hL = h0 + r;
                    *(unsigned short*)(smem + OFF_GT + hL * 64 +
                                       ((g * 2) ^ (((hL >> 2) & 3) << 4))) = f2bf(gv);
                }
                __builtin_nontemporal_store(gs,
                    (f32x4*)(gate_b + (size_t)(gtile + g) * G_ + htile + h0));
            }

        // [B2] gate^T visible; stores keep sailing (no vmcnt)
        LGKM0; SBAR; SCHED0;

        // ---- agg[h][u] += gate^T @ fT  (K = g32; A from GT LDS, B from ft regs) ----
        {
            v8bf ag[2];
            #pragma unroll
            for (int hf = 0; hf < 2; ++hf) {
                int hr = 32 * w + 16 * hf + l15;
                ag[hf] = *(const v8bf*)(smem + OFF_GT + hr * 64 +
                                        ((l4 * 16) ^ (((hr >> 2) & 3) << 4)));
            }
            #pragma unroll
            for (int hf = 0; hf < 2; ++hf)
                #pragma unroll
                for (int u4 = 0; u4 < 8; ++u4)
                    agga[hf][u4] = __builtin_amdgcn_mfma_f32_16x16x32_bf16(ag[hf], ft[u4], agga[hf][u4], 0, 0, 0);
        }
    }

    // write agg partial
    #pragma unroll
    for (int hf = 0; hf < 2; ++hf)
        #pragma unroll
        for (int u4 = 0; u4 < 8; ++u4)
            #pragma unroll
            for (int r = 0; r < 4; ++r) {
                int h = htile + 32 * w + 16 * hf + 4 * l4 + r;
                int u = 16 * u4 + l15;
                part[(((size_t)b * 4 + split) << 19) + (size_t)h * U_ + u] = agga[hf][u4][r];
            }
}

// ---------------- reduce: out = relu(part0..3 + g2) (g2 already in d_out) ----------------
__global__ __launch_bounds__(256) void k_reduce(const float4* __restrict__ part, float4* __restrict__ outio)
{
    int i = blockIdx.x * 256 + threadIdx.x;     // 0..524287 float4s
    int fb = i >> 17, r = i & 0x1FFFF;
    const float4* p = part + (((size_t)fb * 4) << 17) + r;
    float4 p0 = p[0];
    float4 p1 = p[(size_t)1 << 17];
    float4 p2 = p[(size_t)2 << 17];
    float4 p3 = p[(size_t)3 << 17];
    float4 g = outio[i];
    float4 o;
    o.x = fmaxf(p0.x + p1.x + p2.x + p3.x + g.x, 0.f);
    o.y = fmaxf(p0.y + p1.y + p2.y + p3.y + g.y, 0.f);
    o.z = fmaxf(p0.z + p1.z + p2.z + p3.z + g.z, 0.f);
    o.w = fmaxf(p0.w + p1.w + p2.w + p3.w + g.w, 0.f);
    outio[i] = o;
}

extern "C" void kernel_launch(void* const* d_in, const int* in_sizes, int n_in,
                              void* d_out, int out_size, void* d_ws, size_t ws_size,
                              hipStream_t stream)
{
    (void)in_sizes; (void)n_in; (void)out_size; (void)ws_size;
    const float* x   = (const float*)d_in[0];
    const float* adj = (const float*)d_in[1];
    const float* w   = (const float*)d_in[2];
    const float* ai  = (const float*)d_in[3];
    const float* aj  = (const float*)d_in[4];
    const float* w2  = (const float*)d_in[5];
    const float* ba  = (const float*)d_in[6];

    char* ws = (char*)d_ws;
    unsigned short* Ff  = (unsigned short*)(ws);                        // 4 MiB
    unsigned short* FfT = (unsigned short*)(ws + ((size_t)4 << 20));    // 4 MiB
    unsigned short* Ai  = (unsigned short*)(ws + ((size_t)8 << 20));    // 1 MiB
    unsigned short* Aj  = (unsigned short*)(ws + ((size_t)9 << 20));    // 1 MiB
    unsigned short* wT  = (unsigned short*)(ws + ((size_t)10 << 20));   // 64 KiB
    unsigned short* w2T = (unsigned short*)(ws + ((size_t)10 << 20) + (1 << 17));
    float* part         = (float*)(ws + ((size_t)12 << 20));            // 32 MiB [B][4][G][U]
    unsigned short* ct16= (unsigned short*)(ws + ((size_t)44 << 20));   // 32 MiB bf16 fused bias

    float* out  = (float*)d_out;                       // [B*G*U]
    float* gate = out + (size_t)B_ * G_ * U_;          // [B*G*G]

    k_transpose_w   <<<dim3(16),   dim3(256), 0, stream>>>(w, w2, wT, w2T);
    k_transpose_aiaj<<<dim3(128),  dim3(256), 0, stream>>>(ai, aj, Ai, Aj);
    k_bias16        <<<dim3(8192), dim3(256), 0, stream>>>(adj, ba, ct16);
    k_gemm_f        <<<dim3(128),  dim3(256), 0, stream>>>(x, wT, w2T, Ff, FfT, out);
    k_main          <<<dim3(512),  dim3(256), 0, stream>>>(Ff, FfT, Ai, Aj, ct16, gate, part);
    k_reduce        <<<dim3(2048), dim3(256), 0, stream>>>((const float4*)part, (float4*)out);
}

// Round 12
// 158.069 us; speedup vs baseline: 5.3767x; 1.0047x over previous
//
#include <hip/hip_runtime.h>
#include <hip/hip_bf16.h>

#define B_ 4
#define G_ 4096
#define F_ 256
#define U_ 128

typedef __bf16 v8bf __attribute__((ext_vector_type(8)));
typedef float f32x4 __attribute__((ext_vector_type(4)));

__device__ __forceinline__ unsigned short f2bf(float x) {
    union { float f; unsigned u; } v; v.f = x;
    unsigned r = v.u + 0x7FFFu + ((v.u >> 16) & 1u);
    return (unsigned short)(r >> 16);
}
__device__ __forceinline__ float bf2f(unsigned short s) {
    union { unsigned u; float f; } v; v.u = ((unsigned)s) << 16; return v.f;
}

typedef const __attribute__((address_space(1))) unsigned int* gas_t;
typedef __attribute__((address_space(3))) unsigned int* las_t;

// async global->LDS, 16B/lane; LDS dest = uniform base + lane*16; global src per-lane
__device__ __forceinline__ void gld16(const void* g, const void* l) {
    __builtin_amdgcn_global_load_lds((gas_t)(unsigned long long)g,
                                     (las_t)(unsigned)(unsigned long long)l, 16, 0, 0);
}

#define WAITV(n) asm volatile("s_waitcnt vmcnt(" #n ")" ::: "memory")
#define LGKM0    asm volatile("s_waitcnt lgkmcnt(0)" ::: "memory")
#define SBAR     __builtin_amdgcn_s_barrier()
#define SCHED0   __builtin_amdgcn_sched_barrier(0)

// Fragment-major convention: [row16-blk][k32-blk][lane][8 bf16];
// lane = ((k>>3)&3)*16 + (row&15). One frag load = 1KB coalesced / contiguous LDS.

// LDS arena (81920 B = exactly 2 blocks/CU at 256 threads; TRIPLE-buffered staging)
#define OFF_FG   0        // 3 x 8KB: Ff[g32] frags (attn B-side, term 1)
#define OFF_AJ   24576    // 3 x 8KB: Aj[g32] frags (attn B-side, term 2)
#define OFF_BA   49152    // 3 x 8KB: fused bias bf16 [g32][h128], 16B-XOR-swizzled rows
#define OFF_GT   73728    // 8KB: gate^T bf16 [h128][g32], swz ^((h>>2)&3)<<4
#define LDS_SZ   81920

// ---------------- prep: transpose w,w2 [256][128]f32 -> wT [128][256]bf16 ----------------
__global__ __launch_bounds__(256) void k_transpose_w(
    const float* __restrict__ w, const float* __restrict__ w2,
    unsigned short* __restrict__ wT, unsigned short* __restrict__ w2T)
{
    int bx = blockIdx.x;
    const float* src = (bx & 1) ? w2 : w;
    unsigned short* dst = (bx & 1) ? w2T : wT;
    int u = threadIdx.x & 127;
    int kseg = (threadIdx.x >> 7) + (bx >> 1) * 2;   // 0..15
    #pragma unroll
    for (int k = 0; k < 16; ++k) {
        int kk = kseg * 16 + k;
        dst[(size_t)u * F_ + kk] = f2bf(src[(size_t)kk * U_ + u]);
    }
}

// ---------------- prep: ai,aj [128][4096]f32 -> Ai/Aj fragment-major bf16 (1 MiB each) ---
__global__ __launch_bounds__(256) void k_transpose_aiaj(
    const float* __restrict__ ai, const float* __restrict__ aj,
    unsigned short* __restrict__ Ai, unsigned short* __restrict__ Aj)
{
    __shared__ unsigned short s_t[64 * 128];
    int blk = blockIdx.x;
    const float* src = (blk < 64) ? ai : aj;
    unsigned short* dst = (blk < 64) ? Ai : Aj;
    int gtile = (blk & 63) * 64;
    int tid = threadIdx.x;
    int gl = tid & 63, ub = tid >> 6;
    #pragma unroll
    for (int i = 0; i < 32; ++i) {
        int u = ub * 32 + i;
        float v = src[(size_t)u * G_ + gtile + gl];
        int ad = ((gl << 8) + (u << 1)) ^ ((gl & 7) << 4);
        *(unsigned short*)((char*)s_t + ad) = f2bf(v);
    }
    __syncthreads();
    int c = tid >> 4, sub = tid & 15;
    int g4l = c >> 2, k5 = c & 3;
    #pragma unroll
    for (int q = 0; q < 4; ++q) {
        int l = sub * 4 + q;
        int g = g4l * 16 + (l & 15);
        int u = k5 * 32 + (l >> 4) * 8;
        uint4 v = *(const uint4*)((const char*)s_t + (g << 8) + ((u << 1) ^ ((g & 7) << 4)));
        *(uint4*)(dst + (((size_t)((gtile >> 4) + g4l) * 4 + k5) * 64 + l) * 8) = v;
    }
}

// ---------------- prep: fused bias bf16: ct16[g][h] = bf16(b_a + 1e9*adj - 1e9) ----------
__global__ __launch_bounds__(256) void k_bias16(
    const float* __restrict__ adj, const float* __restrict__ ba,
    unsigned short* __restrict__ ct)
{
    size_t i = ((size_t)blockIdx.x * 256 + threadIdx.x) * 8;
    float4 a0 = *(const float4*)(adj + i);
    float4 a1 = *(const float4*)(adj + i + 4);
    float4 b0 = *(const float4*)(ba + i);
    float4 b1 = *(const float4*)(ba + i + 4);
    union { unsigned short s[8]; uint4 v; } o;
    o.s[0] = f2bf(fmaf(a0.x, 1e9f, -1e9f) + b0.x);
    o.s[1] = f2bf(fmaf(a0.y, 1e9f, -1e9f) + b0.y);
    o.s[2] = f2bf(fmaf(a0.z, 1e9f, -1e9f) + b0.z);
    o.s[3] = f2bf(fmaf(a0.w, 1e9f, -1e9f) + b0.w);
    o.s[4] = f2bf(fmaf(a1.x, 1e9f, -1e9f) + b1.x);
    o.s[5] = f2bf(fmaf(a1.y, 1e9f, -1e9f) + b1.y);
    o.s[6] = f2bf(fmaf(a1.z, 1e9f, -1e9f) + b1.z);
    o.s[7] = f2bf(fmaf(a1.w, 1e9f, -1e9f) + b1.w);
    *(uint4*)(ct + i) = o.v;
}

// ---------------- f = bf16(x@w) -> Ff/FfT fragment-major, g2 = f32(x@w_2) -> d_out -------
__global__ __launch_bounds__(256, 2) void k_gemm_f(
    const float* __restrict__ x,
    const unsigned short* __restrict__ wT, const unsigned short* __restrict__ w2T,
    unsigned short* __restrict__ Ff, unsigned short* __restrict__ FfT,
    float* __restrict__ g2_out)
{
    __shared__ unsigned short s_xa[128 * 128];
    __shared__ unsigned short s_w[128 * 128];
    __shared__ unsigned short s_w2[128 * 128];
    const int tid = threadIdx.x;
    const int lane = tid & 63, w = tid >> 6;
    const int l15 = lane & 15, l4 = lane >> 4;
    const int wm = w >> 1, wn = w & 1;
    const int mrow0 = blockIdx.x * 128;

    f32x4 zz = {0.f, 0.f, 0.f, 0.f};
    f32x4 accf[4][4], accg[4][4];
    #pragma unroll
    for (int i = 0; i < 4; ++i)
        #pragma unroll
        for (int j = 0; j < 4; ++j) { accf[i][j] = zz; accg[i][j] = zz; }

    for (int kc = 0; kc < 2; ++kc) {
        if (kc) __syncthreads();
        {   // stage x tile (f32 -> bf16, swizzled)
            int m = tid >> 1, half = tid & 1;
            const float* src = x + (size_t)(mrow0 + m) * F_ + kc * 128 + half * 64;
            unsigned tmp32[32];
            #pragma unroll
            for (int i = 0; i < 16; ++i) {
                float4 v = *(const float4*)(src + i * 4);
                tmp32[i * 2 + 0] = (unsigned)f2bf(v.x) | ((unsigned)f2bf(v.y) << 16);
                tmp32[i * 2 + 1] = (unsigned)f2bf(v.z) | ((unsigned)f2bf(v.w) << 16);
            }
            #pragma unroll
            for (int gi2 = 0; gi2 < 8; ++gi2) {
                int ad = (m << 8) + ((half * 128 + gi2 * 16) ^ ((m & 7) << 4));
                *(uint4*)((char*)s_xa + ad) = *(const uint4*)(tmp32 + gi2 * 4);
            }
        }
        #pragma unroll
        for (int i = 0; i < 8; ++i) {
            int c = w * 8 + i;
            int row = c * 4 + l4;
            int Wp = (l15 << 4) ^ ((row & 7) << 4);
            gld16((const char*)wT  + (size_t)row * 512 + kc * 256 + Wp, (const char*)s_w  + c * 1024);
            gld16((const char*)w2T + (size_t)row * 512 + kc * 256 + Wp, (const char*)s_w2 + c * 1024);
        }
        __syncthreads();
        #pragma unroll
        for (int ks = 0; ks < 4; ++ks) {
            int kb = 64 * ks + 16 * l4;
            v8bf a[4], b1[4], b2[4];
            #pragma unroll
            for (int mf = 0; mf < 4; ++mf) {
                int m = l15 + 16 * mf + 64 * wm;
                int ad = (m << 8) + (kb ^ ((m & 7) << 4));
                a[mf] = *(const v8bf*)((const char*)s_xa + ad);
            }
            #pragma unroll
            for (int nf = 0; nf < 4; ++nf) {
                int u = l15 + 16 * nf + 64 * wn;
                int ad = (u << 8) + (kb ^ ((u & 7) << 4));
                b1[nf] = *(const v8bf*)((const char*)s_w + ad);
                b2[nf] = *(const v8bf*)((const char*)s_w2 + ad);
            }
            #pragma unroll
            for (int mf = 0; mf < 4; ++mf)
                #pragma unroll
                for (int nf = 0; nf < 4; ++nf) {
                    accf[mf][nf] = __builtin_amdgcn_mfma_f32_16x16x32_bf16(a[mf], b1[nf], accf[mf][nf], 0, 0, 0);
                    accg[mf][nf] = __builtin_amdgcn_mfma_f32_16x16x32_bf16(a[mf], b2[nf], accg[mf][nf], 0, 0, 0);
                }
        }
    }
    const int b = mrow0 >> 12, gb = mrow0 & 4095;
    #pragma unroll
    for (int mf = 0; mf < 4; ++mf)
        #pragma unroll
        for (int nf = 0; nf < 4; ++nf)
            #pragma unroll
            for (int r = 0; r < 4; ++r) {
                int m = 4 * l4 + r + 16 * mf + 64 * wm;
                int u = l15 + 16 * nf + 64 * wn;
                g2_out[(size_t)(mrow0 + m) * U_ + u] = accg[mf][nf][r];
            }
    __syncthreads();
    #pragma unroll
    for (int mf = 0; mf < 4; ++mf)
        #pragma unroll
        for (int nf = 0; nf < 4; ++nf)
            #pragma unroll
            for (int r = 0; r < 4; ++r) {
                int m = 4 * l4 + r + 16 * mf + 64 * wm;
                int u = l15 + 16 * nf + 64 * wn;
                int ad = (m << 8) + ((u << 1) ^ ((m & 7) << 4));
                *(unsigned short*)((char*)s_xa + ad) = f2bf(accf[mf][nf][r]);
            }
    __syncthreads();
    {
        unsigned short* Ffb = Ff + (size_t)b * (G_ * U_);
        int c = tid >> 3, sub = tid & 7;
        int g4l = c >> 2, k5 = c & 3;
        #pragma unroll
        for (int q = 0; q < 8; ++q) {
            int l = sub * 8 + q;
            int m = g4l * 16 + (l & 15);
            int k = k5 * 32 + (l >> 4) * 8;
            uint4 v = *(const uint4*)((const char*)s_xa + (m << 8) + ((k << 1) ^ ((m & 7) << 4)));
            *(uint4*)(Ffb + (((size_t)((gb >> 4) + g4l) * 4 + k5) * 64 + l) * 8) = v;
        }
    }
    {
        unsigned short* FfTb = FfT + (size_t)b * (G_ * U_);
        int c = tid >> 3, sub = tid & 7;
        int u4 = c >> 2, g5l = c & 3;
        #pragma unroll
        for (int q = 0; q < 8; ++q) {
            int l = sub * 8 + q;
            int u = u4 * 16 + (l & 15);
            int g0l = g5l * 32 + (l >> 4) * 8;
            union { unsigned short s[8]; uint4 v; } pk;
            #pragma unroll
            for (int j = 0; j < 8; ++j) {
                int m = g0l + j;
                pk.s[j] = *(const unsigned short*)((const char*)s_xa + (m << 8) + ((u << 1) ^ ((m & 7) << 4)));
            }
            *(uint4*)(FfTb + (((size_t)u4 * 128 + (gb >> 5) + g5l) * 64 + l) * 8) = pk.v;
        }
    }
}

// ---------------- k_main helpers ----------------
// Stage FG + AJ + BA for tile gt into buffer `slot` (0..2): 6 gld16/thread (4 waves).
__device__ __forceinline__ void stage_all(const unsigned short* Ff_b, const unsigned short* Aj,
                                          const unsigned short* ct, char* smem,
                                          int w, int lane, int gt, int htile, int slot)
{
    #pragma unroll
    for (int i = 0; i < 2; ++i) {
        int c = 2 * w + i;                  // 0..7
        size_t off = ((((size_t)(gt >> 4) + (c >> 2)) * 4 + (c & 3)) * 64 + lane) * 16;
        gld16((const char*)Ff_b + off, smem + OFF_FG + slot * 8192 + c * 1024);
        gld16((const char*)Aj  + off, smem + OFF_AJ + slot * 8192 + c * 1024);
        int row = 4 * c + (lane >> 4);
        int src = ((lane & 15) * 16) ^ ((row & 7) << 4);
        gld16((const char*)ct + ((size_t)(gt + row) * G_ + htile) * 2 + src,
              smem + OFF_BA + slot * 8192 + c * 1024);
    }
}

// 256 thr / 4 waves; wave w owns h-rows [32w,32w+32). Tile: 128h x 32g per iter, 32 iters.
// TRIPLE-buffered staging, 2 iterations of latency cover.
// Per-thread VMEM order per iter: [1] ft(it) 8   [2] stage(it+2) 6   B1   attn
//   epi[4 nt-stores]   B2   agg.
// FIFO at B1(it): newer-than-stage(it) = st(it-2)4 + ft(it-1)8 + stage(it+1)6 +
//   st(it-1)4 + ft(it)8 + stage(it+2)6 = 36 -> WAITV(32) retires stage(it) (+2-iter-old
//   stores only). Prologue primes stage(0),stage(1); WAITV(6) covers B1(0); B1(1)'s
//   newer-count is exactly 32.
__global__ __launch_bounds__(256, 2) void k_main(
    const unsigned short* __restrict__ Ff,   // [B] frag-major f [g4][k5][lane][8]
    const unsigned short* __restrict__ FfT,  // [B] frag-major fT [u4][g5][lane][8]
    const unsigned short* __restrict__ Ai,   // frag-major aiT
    const unsigned short* __restrict__ Aj,   // frag-major ajT
    const unsigned short* __restrict__ ct16, // [G][G] bf16 fused bias (b_a - 1e9*(1-adj))
    float* __restrict__ gate_out,            // [B][G][G] f32
    float* __restrict__ part)                // [B][4][G][U] f32
{
    __shared__ __align__(1024) char smem[LDS_SZ];
    const int tid = threadIdx.x;
    const int lane = tid & 63, w = tid >> 6;     // w in 0..3
    const int l15 = lane & 15, l4 = lane >> 4;
    // XCD cluster (R8-style): 4 batches of one (split,htile) tile share an XCD.
    // Per-XCD L2 working set ~2 MB (Aj + ct16 slices shared; FfT slice 128KB/block) -> L2-fit.
    const int bid = blockIdx.x;
    const int xcd = bid & 7;
    const int rest = bid >> 3;                   // 0..63
    const int b = rest & 3;
    const int tile = (rest >> 2) * 8 + xcd;      // 0..127
    const int split = tile & 3;
    const int htile = (tile >> 2) * 128;

    const unsigned short* Ff_b  = Ff  + (size_t)b * (G_ * U_);
    const unsigned short* FfT_b = FfT + (size_t)b * (G_ * U_);
    float* gate_b = gate_out + ((size_t)b << 24);

    // ---- prologue: Ai[htile] then Ff[htile] via LDS into per-wave registers (h32/wave) ----
    #pragma unroll
    for (int i = 0; i < 8; ++i) {
        int c = 8 * w + i;                  // 0..31
        size_t off = ((((size_t)(htile >> 4) + (c >> 2)) * 4 + (c & 3)) * 64 + lane) * 16;
        gld16((const char*)Ai + off, smem + c * 1024);
    }
    WAITV(0); SBAR;
    v8bf aih[2][4], fh[2][4];
    #pragma unroll
    for (int hf = 0; hf < 2; ++hf)
        #pragma unroll
        for (int ks = 0; ks < 4; ++ks)
            aih[hf][ks] = *(const v8bf*)(smem + (8 * w + 4 * hf + ks) * 1024 + lane * 16);
    LGKM0; SBAR;
    #pragma unroll
    for (int i = 0; i < 8; ++i) {
        int c = 8 * w + i;
        size_t off = ((((size_t)(htile >> 4) + (c >> 2)) * 4 + (c & 3)) * 64 + lane) * 16;
        gld16((const char*)Ff_b + off, smem + c * 1024);
    }
    WAITV(0); SBAR;
    #pragma unroll
    for (int hf = 0; hf < 2; ++hf)
        #pragma unroll
        for (int ks = 0; ks < 4; ++ks)
            fh[hf][ks] = *(const v8bf*)(smem + (8 * w + 4 * hf + ks) * 1024 + lane * 16);
    LGKM0; SBAR;
    // prime stage(0) -> slot 0, stage(1) -> slot 1; wait only for stage(0)
    stage_all(Ff_b, Aj, ct16, smem, w, lane, split * 1024, htile, 0);
    stage_all(Ff_b, Aj, ct16, smem, w, lane, split * 1024 + 32, htile, 1);
    WAITV(6);

    f32x4 zz = {0.f, 0.f, 0.f, 0.f};
    f32x4 agga[2][8];
    #pragma unroll
    for (int i = 0; i < 2; ++i)
        #pragma unroll
        for (int j = 0; j < 8; ++j) agga[i][j] = zz;

    int sl = 0;                                   // slot of iter it (= it % 3)
    for (int it = 0; it < 32; ++it) {
        const int gtile = split * 1024 + it * 32;
        const int itn = (it < 30) ? it + 2 : 31;  // clamp: same op count, no OOB
        const int gnext = split * 1024 + itn * 32;
        int sl2 = sl + 2; if (sl2 >= 3) sl2 -= 3; // slot of it+2

        // [1] ft(it): agg B-frags direct from L2 (FfT_b slice resident on this XCD)
        v8bf ft[8];
        #pragma unroll
        for (int u4 = 0; u4 < 8; ++u4)
            ft[u4] = *(const v8bf*)(FfT_b + (((size_t)u4 * 128 + (gtile >> 5)) * 64 + lane) * 8);

        // [2] stage(it+2) -> slot sl2 (2 full iterations of latency cover)
        stage_all(Ff_b, Aj, ct16, smem, w, lane, gnext, htile, sl2);

        // [B1] stage(it) in LDS; own prior-iter LDS reads drained (GT overwrite safe)
        WAITV(32); LGKM0; SBAR; SCHED0;

        // ---- attn: acc[h][g] = ai[:,h]·f[g] + f[h]·aj[:,g]  (32h x 32g per wave) ----
        f32x4 acc[2][2];
        #pragma unroll
        for (int i = 0; i < 2; ++i)
            #pragma unroll
            for (int j = 0; j < 2; ++j) acc[i][j] = zz;
        {
            const char* bfg = smem + OFF_FG + sl * 8192;
            const char* baj = smem + OFF_AJ + sl * 8192;
            #pragma unroll
            for (int ks = 0; ks < 4; ++ks) {
                v8bf fgv[2], ajv[2];
                #pragma unroll
                for (int gf = 0; gf < 2; ++gf) {
                    fgv[gf] = *(const v8bf*)(bfg + (gf * 4 + ks) * 1024 + lane * 16);
                    ajv[gf] = *(const v8bf*)(baj + (gf * 4 + ks) * 1024 + lane * 16);
                }
                #pragma unroll
                for (int hf = 0; hf < 2; ++hf)
                    #pragma unroll
                    for (int gf = 0; gf < 2; ++gf) {
                        acc[hf][gf] = __builtin_amdgcn_mfma_f32_16x16x32_bf16(aih[hf][ks], fgv[gf], acc[hf][gf], 0, 0, 0);
                        acc[hf][gf] = __builtin_amdgcn_mfma_f32_16x16x32_bf16(fh[hf][ks],  ajv[gf], acc[hf][gf], 0, 0, 0);
                    }
            }
        }

        // ---- epilogue: fused bias + sigmoid -> gate (nt f32x4) + gate^T (LDS bf16) ----
        #pragma unroll
        for (int gf = 0; gf < 2; ++gf)
            #pragma unroll
            for (int hf = 0; hf < 2; ++hf) {
                int g = 16 * gf + l15;               // tile-local g row
                int h0 = 32 * w + 16 * hf + 4 * l4;  // htile-local h
                ushort4 bu = *(const ushort4*)(smem + OFF_BA + sl * 8192 + g * 256 +
                                               ((h0 * 2) ^ ((g & 7) << 4)));
                f32x4 gs;
                #pragma unroll
                for (int r = 0; r < 4; ++r) {
                    float attnv = acc[hf][gf][r] + bf2f((&bu.x)[r]);
                    float e = __expf(-attnv);
                    float gv = __builtin_amdgcn_rcpf(1.0f + e);   // non-edge -> exactly 0
                    gs[r] = gv;
                    int hL = h0 + r;
                    *(unsigned short*)(smem + OFF_GT + hL * 64 +
                                       ((g * 2) ^ (((hL >> 2) & 3) << 4))) = f2bf(gv);
                }
                __builtin_nontemporal_store(gs,
                    (f32x4*)(gate_b + (size_t)(gtile + g) * G_ + htile + h0));
            }

        // [B2] gate^T visible; stores keep sailing (no vmcnt)
        LGKM0; SBAR; SCHED0;

        // ---- agg[h][u] += gate^T @ fT  (K = g32; A from GT LDS, B from ft regs) ----
        {
            v8bf ag[2];
            #pragma unroll
            for (int hf = 0; hf < 2; ++hf) {
                int hr = 32 * w + 16 * hf + l15;
                ag[hf] = *(const v8bf*)(smem + OFF_GT + hr * 64 +
                                        ((l4 * 16) ^ (((hr >> 2) & 3) << 4)));
            }
            #pragma unroll
            for (int hf = 0; hf < 2; ++hf)
                #pragma unroll
                for (int u4 = 0; u4 < 8; ++u4)
                    agga[hf][u4] = __builtin_amdgcn_mfma_f32_16x16x32_bf16(ag[hf], ft[u4], agga[hf][u4], 0, 0, 0);
        }

        sl = (sl + 1 == 3) ? 0 : sl + 1;
    }

    // write agg partial
    #pragma unroll
    for (int hf = 0; hf < 2; ++hf)
        #pragma unroll
        for (int u4 = 0; u4 < 8; ++u4)
            #pragma unroll
            for (int r = 0; r < 4; ++r) {
                int h = htile + 32 * w + 16 * hf + 4 * l4 + r;
                int u = 16 * u4 + l15;
                part[(((size_t)b * 4 + split) << 19) + (size_t)h * U_ + u] = agga[hf][u4][r];
            }
}

// ---------------- reduce: out = relu(part0..3 + g2) (g2 already in d_out) ----------------
__global__ __launch_bounds__(256) void k_reduce(const float4* __restrict__ part, float4* __restrict__ outio)
{
    int i = blockIdx.x * 256 + threadIdx.x;     // 0..524287 float4s
    int fb = i >> 17, r = i & 0x1FFFF;
    const float4* p = part + (((size_t)fb * 4) << 17) + r;
    float4 p0 = p[0];
    float4 p1 = p[(size_t)1 << 17];
    float4 p2 = p[(size_t)2 << 17];
    float4 p3 = p[(size_t)3 << 17];
    float4 g = outio[i];
    float4 o;
    o.x = fmaxf(p0.x + p1.x + p2.x + p3.x + g.x, 0.f);
    o.y = fmaxf(p0.y + p1.y + p2.y + p3.y + g.y, 0.f);
    o.z = fmaxf(p0.z + p1.z + p2.z + p3.z + g.z, 0.f);
    o.w = fmaxf(p0.w + p1.w + p2.w + p3.w + g.w, 0.f);
    outio[i] = o;
}

extern "C" void kernel_launch(void* const* d_in, const int* in_sizes, int n_in,
                              void* d_out, int out_size, void* d_ws, size_t ws_size,
                              hipStream_t stream)
{
    (void)in_sizes; (void)n_in; (void)out_size; (void)ws_size;
    const float* x   = (const float*)d_in[0];
    const float* adj = (const float*)d_in[1];
    const float* w   = (const float*)d_in[2];
    const float* ai  = (const float*)d_in[3];
    const float* aj  = (const float*)d_in[4];
    const float* w2  = (const float*)d_in[5];
    const float* ba  = (const float*)d_in[6];

    char* ws = (char*)d_ws;
    unsigned short* Ff  = (unsigned short*)(ws);                        // 4 MiB
    unsigned short* FfT = (unsigned short*)(ws + ((size_t)4 << 20));    // 4 MiB
    unsigned short* Ai  = (unsigned short*)(ws + ((size_t)8 << 20));    // 1 MiB
    unsigned short* Aj  = (unsigned short*)(ws + ((size_t)9 << 20));    // 1 MiB
    unsigned short* wT  = (unsigned short*)(ws + ((size_t)10 << 20));   // 64 KiB
    unsigned short* w2T = (unsigned short*)(ws + ((size_t)10 << 20) + (1 << 17));
    float* part         = (float*)(ws + ((size_t)12 << 20));            // 32 MiB [B][4][G][U]
    unsigned short* ct16= (unsigned short*)(ws + ((size_t)44 << 20));   // 32 MiB bf16 fused bias

    float* out  = (float*)d_out;                       // [B*G*U]
    float* gate = out + (size_t)B_ * G_ * U_;          // [B*G*G]

    k_transpose_w   <<<dim3(16),   dim3(256), 0, stream>>>(w, w2, wT, w2T);
    k_transpose_aiaj<<<dim3(128),  dim3(256), 0, stream>>>(ai, aj, Ai, Aj);
    k_bias16        <<<dim3(8192), dim3(256), 0, stream>>>(adj, ba, ct16);
    k_gemm_f        <<<dim3(128),  dim3(256), 0, stream>>>(x, wT, w2T, Ff, FfT, out);
    k_main          <<<dim3(512),  dim3(256), 0, stream>>>(Ff, FfT, Ai, Aj, ct16, gate, part);
    k_reduce        <<<dim3(2048), dim3(256), 0, stream>>>((const float4*)part, (float4*)out);
}